// Round 22
// baseline (112.188 us; speedup 1.0000x reference)
//
#include <hip/hip_runtime.h>

// VQ codebook via MFMA: z_e (262144,64) f32, embeddings (512,64) f32.
// Outputs (flat f32): z_q_st [N*D], indices-as-float [N], loss [1].
//
// R22 = R21 (persistent 128KB codebook in LDS, 1 block/CU, zero-barrier main
// loop) with 4 TOKEN-GROUPS PER WAVE (64 tokens, one pass): each E-fragment
// read feeds 4 independent MFMA chains (24 MFMA/tile). Key insight from R21
// counters: LDS pins residency at 16 waves/CU regardless of VGPRs -> the
// 128-VGPR/thread budget is FREE (we used 56). Spent on: 16 named z-frags
// (rule #20: no runtime indexing), 4 C accumulators, 4x argmin state.
// E-frags kept 2-live (e0 pair -> 12 MFMA -> e1 pair -> 12 MFMA) to bound
// peak pressure. Per-group MFMA chain order / ARGMIN4 / lane-reduce /
// ballot rescan / THRESH bitwise = R21 (absmax 0 x10 rounds).
// Spill canary: WRITE_SIZE must stay ~67MB.

typedef short  bf16x8 __attribute__((ext_vector_type(8)));
typedef float  f32x4  __attribute__((ext_vector_type(4)));

static constexpr int N_TOK = 262144;
static constexpr int K     = 512;
static constexpr int D     = 64;
static constexpr float THRESH = 0.01f;
static constexpr int NBLK_A = N_TOK / 1024;   // 256 blocks (1 per CU)

// ws layout (bytes)
static constexpr size_t WS_ESQ   = 0;         //  512 f32 (2048 B)
static constexpr size_t WS_BL    = 2048;      //  256 f32 (1024 B)
static constexpr size_t WS_EFRAG = 10240;     // 65536 u16 (131072 B), 16B-al

#define GLDS16(G, L) __builtin_amdgcn_global_load_lds(                    \
    (const __attribute__((address_space(1))) void*)(G),                   \
    (__attribute__((address_space(3))) void*)(L), 16, 0, 0)

// ---- prep: E' = -2E -> bf16 hi/lo A-frags, fused with esq ------------------
__global__ __launch_bounds__(512) void prep_kernel(
    const float* __restrict__ emb, unsigned short* __restrict__ ef,
    float* __restrict__ esq) {
  int idx  = blockIdx.x * 512 + threadIdx.x;   // 32768 = 512 codes * 64 d
  int code = idx >> 6, d = idx & 63;
  float s  = -2.0f * emb[code * 64 + d];
  unsigned u  = __float_as_uint(s);
  unsigned hi = (u + 0x7FFFu + ((u >> 16) & 1u)) >> 16;       // RNE bf16
  float lof   = s - __uint_as_float(hi << 16);
  unsigned v2 = __float_as_uint(lof);
  unsigned lo = (v2 + 0x7FFFu + ((v2 >> 16) & 1u)) >> 16;     // RNE bf16
  int tile = code >> 4, row = code & 15;
  int c = (d >> 5) & 1, g = (d >> 3) & 3, i = d & 7;
  int lane = row + (g << 4);
  size_t base = ((size_t)tile * 256 + (size_t)c * 128) * 8;
  ef[base + (size_t)(0 * 64 + lane) * 8 + i] = (unsigned short)hi;
  ef[base + (size_t)(1 * 64 + lane) * 8 + i] = (unsigned short)lo;
  // esq for this block's 8 codes (rows L1-hot from the reads above).
  if (threadIdx.x < 8) {
    int k = blockIdx.x * 8 + threadIdx.x;
    const float4* row4 = reinterpret_cast<const float4*>(emb + (size_t)k * D);
    float acc = 0.f;
#pragma unroll
    for (int j = 0; j < 16; ++j) {
      float4 v = row4[j];
      acc = fmaf(v.x, v.x, acc); acc = fmaf(v.y, v.y, acc);
      acc = fmaf(v.z, v.z, acc); acc = fmaf(v.w, v.w, acc);
    }
    esq[k] = acc;
  }
}

// RNE bf16 two-term split of 8 floats -> hi/lo bf16x8.
__device__ __forceinline__ void split8(float4 a, float4 b,
                                       bf16x8& h, bf16x8& lo) {
  float v[8] = {a.x, a.y, a.z, a.w, b.x, b.y, b.z, b.w};
#pragma unroll
  for (int i = 0; i < 8; ++i) {
    unsigned u  = __float_as_uint(v[i]);
    unsigned hi = (u + 0x7FFFu + ((u >> 16) & 1u)) >> 16;
    float lof   = v[i] - __uint_as_float(hi << 16);
    unsigned v2 = __float_as_uint(lof);
    unsigned l2 = (v2 + 0x7FFFu + ((v2 >> 16) & 1u)) >> 16;
    h[i]  = (short)hi;
    lo[i] = (short)l2;
  }
}

#define ARGMIN4(C, BASE, BEST, SECOND, BIDXV)               \
  {                                                         \
    _Pragma("unroll")                                       \
    for (int r = 0; r < 4; ++r) {                           \
      float v = (C)[r];                                     \
      bool lt = v < (BEST);                                 \
      float mn = fminf((SECOND), v);                        \
      (SECOND) = lt ? (BEST) : mn;                          \
      (BIDXV)  = lt ? ((BASE) + r) : (BIDXV);               \
      (BEST)   = lt ? v : (BEST);                           \
    }                                                       \
  }

// Load one group's z row pair of 32B segments and split.
#define ZFRAG(ZP, H0, L0, H1, L1)                                          \
  {                                                                        \
    float4 q0 = *reinterpret_cast<const float4*>(ZP);                      \
    float4 q1 = *reinterpret_cast<const float4*>((ZP) + 4);                \
    float4 q2 = *reinterpret_cast<const float4*>((ZP) + 32);               \
    float4 q3 = *reinterpret_cast<const float4*>((ZP) + 36);               \
    split8(q0, q1, H0, L0);                                                \
    split8(q2, q3, H1, L1);                                                \
  }

// ---- kernel A: persistent-codebook MFMA, 64 tokens/wave --------------------
__global__ __launch_bounds__(1024) void vq_mfma(
    const float* __restrict__ z_e, const float* __restrict__ emb,
    const unsigned short* __restrict__ efrag, const float* __restrict__ esq_g,
    float* __restrict__ out_zq, float* __restrict__ out_idx,
    float* __restrict__ block_loss) {
  __shared__ float esql[K];                         // 2 KB
  __shared__ __align__(16) short lds_e[65536];      // 128 KB: all 32 tiles
  __shared__ int   sIdx[1024];                      // 4 KB
  __shared__ float wsm[16];

  const int t  = threadIdx.x;                       // 0..1023
  const int l  = t & 63;
  const int wu = __builtin_amdgcn_readfirstlane(t >> 6);  // wave 0..15
  const int g  = l >> 4, g4 = g << 2;
  const int tok0 = blockIdx.x * 1024 + wu * 64;     // wave's 64 tokens

  if (t < K) esql[t] = esq_g[t];

  const bf16x8* EF = reinterpret_cast<const bf16x8*>(efrag);
  // Stage the whole codebook frag array: 8 rounds x 16KB (1024 thr x 16B).
#pragma unroll
  for (int r = 0; r < 8; ++r)
    GLDS16(EF + r * 1024 + t, &lds_e[r * 8192 + wu * 512]);

  // z frags: 4 groups (rows tok0+16*i+(l&15)), 16 named bf16x8.
  bf16x8 zh0A, zl0A, zh1A, zl1A, zh0B, zl0B, zh1B, zl1B;
  bf16x8 zh0C, zl0C, zh1C, zl1C, zh0D, zl0D, zh1D, zl1D;
  {
    const float* zp = z_e + (size_t)(tok0 + (l & 15)) * D + g * 8;
    ZFRAG(zp, zh0A, zl0A, zh1A, zl1A)
    zp += (size_t)16 * D;
    ZFRAG(zp, zh0B, zl0B, zh1B, zl1B)
    zp += (size_t)16 * D;
    ZFRAG(zp, zh0C, zl0C, zh1C, zl1C)
    zp += (size_t)16 * D;
    ZFRAG(zp, zh0D, zl0D, zh1D, zl1D)
  }

  asm volatile("s_waitcnt vmcnt(0)" ::: "memory");
  __builtin_amdgcn_s_barrier();                     // one-time; none after

  float bestA = 3.402823466e38f, secondA = 3.402823466e38f;
  float bestB = 3.402823466e38f, secondB = 3.402823466e38f;
  float bestC = 3.402823466e38f, secondC = 3.402823466e38f;
  float bestD = 3.402823466e38f, secondD = 3.402823466e38f;
  int idxA = 0, idxB = 0, idxC = 0, idxD = 0;

  for (int tile = 0; tile < 32; ++tile) {           // ascending code order
    const bf16x8* tb =
        reinterpret_cast<const bf16x8*>(&lds_e[(size_t)tile * 2048]);
    f32x4 CA = *reinterpret_cast<const f32x4*>(&esql[tile * 16 + g4]);
    f32x4 CB = CA, CC = CA, CD = CA;
    // k-chunk 0: per-group chain order e0h*zh0, e0h*zl0, e0l*zh0 (== R21).
    {
      bf16x8 e0h = tb[l], e0l = tb[64 + l];
      __builtin_amdgcn_s_setprio(1);
      CA = __builtin_amdgcn_mfma_f32_16x16x32_bf16(e0h, zh0A, CA, 0, 0, 0);
      CB = __builtin_amdgcn_mfma_f32_16x16x32_bf16(e0h, zh0B, CB, 0, 0, 0);
      CC = __builtin_amdgcn_mfma_f32_16x16x32_bf16(e0h, zh0C, CC, 0, 0, 0);
      CD = __builtin_amdgcn_mfma_f32_16x16x32_bf16(e0h, zh0D, CD, 0, 0, 0);
      CA = __builtin_amdgcn_mfma_f32_16x16x32_bf16(e0h, zl0A, CA, 0, 0, 0);
      CB = __builtin_amdgcn_mfma_f32_16x16x32_bf16(e0h, zl0B, CB, 0, 0, 0);
      CC = __builtin_amdgcn_mfma_f32_16x16x32_bf16(e0h, zl0C, CC, 0, 0, 0);
      CD = __builtin_amdgcn_mfma_f32_16x16x32_bf16(e0h, zl0D, CD, 0, 0, 0);
      CA = __builtin_amdgcn_mfma_f32_16x16x32_bf16(e0l, zh0A, CA, 0, 0, 0);
      CB = __builtin_amdgcn_mfma_f32_16x16x32_bf16(e0l, zh0B, CB, 0, 0, 0);
      CC = __builtin_amdgcn_mfma_f32_16x16x32_bf16(e0l, zh0C, CC, 0, 0, 0);
      CD = __builtin_amdgcn_mfma_f32_16x16x32_bf16(e0l, zh0D, CD, 0, 0, 0);
      __builtin_amdgcn_s_setprio(0);
    }
    // k-chunk 1: e1h*zh1, e1h*zl1, e1l*zh1.
    {
      bf16x8 e1h = tb[128 + l], e1l = tb[192 + l];
      __builtin_amdgcn_s_setprio(1);
      CA = __builtin_amdgcn_mfma_f32_16x16x32_bf16(e1h, zh1A, CA, 0, 0, 0);
      CB = __builtin_amdgcn_mfma_f32_16x16x32_bf16(e1h, zh1B, CB, 0, 0, 0);
      CC = __builtin_amdgcn_mfma_f32_16x16x32_bf16(e1h, zh1C, CC, 0, 0, 0);
      CD = __builtin_amdgcn_mfma_f32_16x16x32_bf16(e1h, zh1D, CD, 0, 0, 0);
      CA = __builtin_amdgcn_mfma_f32_16x16x32_bf16(e1h, zl1A, CA, 0, 0, 0);
      CB = __builtin_amdgcn_mfma_f32_16x16x32_bf16(e1h, zl1B, CB, 0, 0, 0);
      CC = __builtin_amdgcn_mfma_f32_16x16x32_bf16(e1h, zl1C, CC, 0, 0, 0);
      CD = __builtin_amdgcn_mfma_f32_16x16x32_bf16(e1h, zl1D, CD, 0, 0, 0);
      CA = __builtin_amdgcn_mfma_f32_16x16x32_bf16(e1l, zh1A, CA, 0, 0, 0);
      CB = __builtin_amdgcn_mfma_f32_16x16x32_bf16(e1l, zh1B, CB, 0, 0, 0);
      CC = __builtin_amdgcn_mfma_f32_16x16x32_bf16(e1l, zh1C, CC, 0, 0, 0);
      CD = __builtin_amdgcn_mfma_f32_16x16x32_bf16(e1l, zh1D, CD, 0, 0, 0);
      __builtin_amdgcn_s_setprio(0);
    }

    const int base = tile * 16 + g4;
    ARGMIN4(CA, base, bestA, secondA, idxA)
    ARGMIN4(CB, base, bestB, secondB, idxB)
    ARGMIN4(CC, base, bestC, secondC, idxC)
    ARGMIN4(CD, base, bestD, secondD, idxD)
  }

  // Reduce each group across lanes {l, l^16, l^32, l^48}; ties -> smaller.
#pragma unroll
  for (int mask = 16; mask <= 32; mask <<= 1) {
    float ob, os; int oi; bool take; float hi2;
#define RED(BEST, SECOND, IDX)                                  \
    ob = __shfl_xor(BEST, mask); oi = __shfl_xor(IDX, mask);    \
    os = __shfl_xor(SECOND, mask);                              \
    hi2 = fmaxf(BEST, ob);                                      \
    SECOND = fminf(SECOND, fminf(os, hi2));                     \
    take = (ob < BEST) || (ob == BEST && oi < IDX);             \
    BEST = take ? ob : BEST; IDX = take ? oi : IDX;
    RED(bestA, secondA, idxA)
    RED(bestB, secondB, idxB)
    RED(bestC, secondC, idxC)
    RED(bestD, secondD, idxD)
#undef RED
  }

  if (l < 16) {
    sIdx[wu * 64 + l]      = idxA;
    sIdx[wu * 64 + 16 + l] = idxB;
    sIdx[wu * 64 + 32 + l] = idxC;
    sIdx[wu * 64 + 48 + l] = idxD;
  }

  // Inline exact rescan of flagged tokens (same-wave 64-bit ballot loop).
  {
    bool fA = (l < 16) && ((secondA - bestA) < THRESH);
    bool fB = (l < 16) && ((secondB - bestB) < THRESH);
    bool fC = (l < 16) && ((secondC - bestC) < THRESH);
    bool fD = (l < 16) && ((secondD - bestD) < THRESH);
    unsigned long long m =  (__ballot(fA) & 0xFFFFull)
                         | ((__ballot(fB) & 0xFFFFull) << 16)
                         | ((__ballot(fC) & 0xFFFFull) << 32)
                         | ((__ballot(fD) & 0xFFFFull) << 48);
    while (m) {
      const int j = __builtin_ctzll(m);
      m &= m - 1;
      const int n = tok0 + j;
      const float4* zr = reinterpret_cast<const float4*>(z_e + (size_t)n * D);
      float best = 3.402823466e38f; int bid = 0;
#pragma unroll 1
      for (int half2 = 0; half2 < 2; ++half2) {
        float acc[4];
#pragma unroll
        for (int mm = 0; mm < 4; ++mm) acc[mm] = 0.f;
#pragma unroll 1
        for (int i = 0; i < 16; ++i) {
          float4 z4 = zr[i];                       // uniform addr broadcast
#pragma unroll
          for (int mm = 0; mm < 4; ++mm) {
            const float4 e4 = *reinterpret_cast<const float4*>(
                emb + (size_t)(l + 64 * (half2 * 4 + mm)) * D + 4 * i);
            acc[mm] = fmaf(z4.x, e4.x, acc[mm]);
            acc[mm] = fmaf(z4.y, e4.y, acc[mm]);
            acc[mm] = fmaf(z4.z, e4.z, acc[mm]);
            acc[mm] = fmaf(z4.w, e4.w, acc[mm]);
          }
        }
#pragma unroll
        for (int mm = 0; mm < 4; ++mm) {
          const int code = l + 64 * (half2 * 4 + mm);
          float s = fmaf(-2.f, acc[mm], esq_g[code]);
          if (s < best) { best = s; bid = code; }  // ascending overall
        }
      }
#pragma unroll
      for (int mk = 1; mk <= 32; mk <<= 1) {       // lexicographic min
        float ob = __shfl_xor(best, mk);
        int   oi = __shfl_xor(bid, mk);
        bool take = (ob < best) || (ob == best && oi < bid);
        best = take ? ob : best;
        bid  = take ? oi : bid;
      }
      if (l == 0) sIdx[wu * 64 + j] = bid;         // same-wave patch
    }
  }
  // No barrier: sIdx[wu*64..+64) produced and consumed by wave wu only.

  // Fused epilogue: 1 lane/token; gather + z_q_st + idx + loss.
  {
    const int n = tok0 + l;
    const int bi = sIdx[wu * 64 + l];
    const float4* er = reinterpret_cast<const float4*>(emb + (size_t)bi * D);
    const float4* zr = reinterpret_cast<const float4*>(z_e + (size_t)n * D);
    float4* orow = reinterpret_cast<float4*>(out_zq + (size_t)n * D);
    float lsum = 0.f;
#pragma unroll 4
    for (int i = 0; i < 16; ++i) {
      float4 Q = er[i], Z = zr[i];
      float dx = Q.x - Z.x, dy = Q.y - Z.y, dz = Q.z - Z.z, dw = Q.w - Z.w;
      float4 st;
      st.x = Z.x + dx; st.y = Z.y + dy; st.z = Z.z + dz; st.w = Z.w + dw;
      orow[i] = st;
      lsum = fmaf(dx, dx, lsum); lsum = fmaf(dy, dy, lsum);
      lsum = fmaf(dz, dz, lsum); lsum = fmaf(dw, dw, lsum);
    }
    out_idx[n] = (float)bi;
    float s = lsum;
#pragma unroll
    for (int off = 32; off > 0; off >>= 1) s += __shfl_xor(s, off, 64);
    if (l == 0) wsm[wu] = s;
  }
  __syncthreads();
  if (t == 0) {
    float s = 0.f;
#pragma unroll
    for (int i = 0; i < 16; ++i) s += wsm[i];      // fixed ascending order
    block_loss[blockIdx.x] = s;
  }
}

// ---- finalize loss (deterministic tree, 256 partials) ----------------------
__global__ __launch_bounds__(256) void loss_finalize(
    const float* __restrict__ bl, float* __restrict__ out_loss) {
  __shared__ float sm[256];
  const int t = threadIdx.x;
  sm[t] = bl[t];
  __syncthreads();
#pragma unroll
  for (int off = 128; off > 0; off >>= 1) {
    if (t < off) sm[t] += sm[t + off];
    __syncthreads();
  }
  if (t == 0) out_loss[0] = sm[0] * (1.0f / 16777216.0f);  // /(N*D)
}

extern "C" void kernel_launch(void* const* d_in, const int* in_sizes, int n_in,
                              void* d_out, int out_size, void* d_ws, size_t ws_size,
                              hipStream_t stream) {
  const float* z_e = (const float*)d_in[0];
  const float* emb = (const float*)d_in[1];

  float* out      = (float*)d_out;
  float* out_zq   = out;                          // N*D
  float* out_idx  = out + (size_t)N_TOK * D;      // N
  float* out_loss = out_idx + N_TOK;              // 1

  char* wsb = (char*)d_ws;
  float*          esqp = (float*)(wsb + WS_ESQ);
  float*          bl   = (float*)(wsb + WS_BL);
  unsigned short* ef   = (unsigned short*)(wsb + WS_EFRAG);

  prep_kernel<<<64, 512, 0, stream>>>(emb, ef, esqp);
  vq_mfma<<<NBLK_A, 1024, 0, stream>>>(z_e, emb, ef, esqp, out_zq, out_idx, bl);
  loss_finalize<<<1, 256, 0, stream>>>(bl, out_loss);
}

// Round 23
// 103.743 us; speedup vs baseline: 1.0814x; 1.0814x over previous
//
#include <hip/hip_runtime.h>

// VQ codebook via MFMA: z_e (262144,64) f32, embeddings (512,64) f32.
// Outputs (flat f32): z_q_st [N*D], indices-as-float [N], loss [1].
//
// R23 = R21 (best, 104us: persistent 128KB codebook, 1 block/CU, 16 waves,
// zero-barrier main loop, 2 token-groups/wave, 56 VGPR) + #pragma unroll 2
// on the tile loop: lets the compiler hoist tile 2k+1's ds_reads above tile
// 2k's MFMA-chain waits (cross-iteration pipelining the rolled loop can't
// express). R22 lesson: the 64-VGPR allocator cap holds in ALL regimes
// (even LDS-pinned occupancy) -- 4 token-groups spilled (WRITE 70MB canary);
// 2 groups is max ILP under the cap. All arithmetic / selection bitwise
// = R21 (absmax 0 x10 rounds).

typedef short  bf16x8 __attribute__((ext_vector_type(8)));
typedef float  f32x4  __attribute__((ext_vector_type(4)));

static constexpr int N_TOK = 262144;
static constexpr int K     = 512;
static constexpr int D     = 64;
static constexpr float THRESH = 0.01f;
static constexpr int NBLK_A = N_TOK / 1024;   // 256 blocks (1 per CU)

// ws layout (bytes)
static constexpr size_t WS_ESQ   = 0;         //  512 f32 (2048 B)
static constexpr size_t WS_BL    = 2048;      //  256 f32 (1024 B)
static constexpr size_t WS_EFRAG = 10240;     // 65536 u16 (131072 B), 16B-al

#define GLDS16(G, L) __builtin_amdgcn_global_load_lds(                    \
    (const __attribute__((address_space(1))) void*)(G),                   \
    (__attribute__((address_space(3))) void*)(L), 16, 0, 0)

// ---- prep: E' = -2E -> bf16 hi/lo A-frags, fused with esq ------------------
__global__ __launch_bounds__(512) void prep_kernel(
    const float* __restrict__ emb, unsigned short* __restrict__ ef,
    float* __restrict__ esq) {
  int idx  = blockIdx.x * 512 + threadIdx.x;   // 32768 = 512 codes * 64 d
  int code = idx >> 6, d = idx & 63;
  float s  = -2.0f * emb[code * 64 + d];
  unsigned u  = __float_as_uint(s);
  unsigned hi = (u + 0x7FFFu + ((u >> 16) & 1u)) >> 16;       // RNE bf16
  float lof   = s - __uint_as_float(hi << 16);
  unsigned v2 = __float_as_uint(lof);
  unsigned lo = (v2 + 0x7FFFu + ((v2 >> 16) & 1u)) >> 16;     // RNE bf16
  int tile = code >> 4, row = code & 15;
  int c = (d >> 5) & 1, g = (d >> 3) & 3, i = d & 7;
  int lane = row + (g << 4);
  size_t base = ((size_t)tile * 256 + (size_t)c * 128) * 8;
  ef[base + (size_t)(0 * 64 + lane) * 8 + i] = (unsigned short)hi;
  ef[base + (size_t)(1 * 64 + lane) * 8 + i] = (unsigned short)lo;
  // esq for this block's 8 codes (rows L1-hot from the reads above).
  if (threadIdx.x < 8) {
    int k = blockIdx.x * 8 + threadIdx.x;
    const float4* row4 = reinterpret_cast<const float4*>(emb + (size_t)k * D);
    float acc = 0.f;
#pragma unroll
    for (int j = 0; j < 16; ++j) {
      float4 v = row4[j];
      acc = fmaf(v.x, v.x, acc); acc = fmaf(v.y, v.y, acc);
      acc = fmaf(v.z, v.z, acc); acc = fmaf(v.w, v.w, acc);
    }
    esq[k] = acc;
  }
}

// RNE bf16 two-term split of 8 floats -> hi/lo bf16x8.
__device__ __forceinline__ void split8(float4 a, float4 b,
                                       bf16x8& h, bf16x8& lo) {
  float v[8] = {a.x, a.y, a.z, a.w, b.x, b.y, b.z, b.w};
#pragma unroll
  for (int i = 0; i < 8; ++i) {
    unsigned u  = __float_as_uint(v[i]);
    unsigned hi = (u + 0x7FFFu + ((u >> 16) & 1u)) >> 16;
    float lof   = v[i] - __uint_as_float(hi << 16);
    unsigned v2 = __float_as_uint(lof);
    unsigned l2 = (v2 + 0x7FFFu + ((v2 >> 16) & 1u)) >> 16;
    h[i]  = (short)hi;
    lo[i] = (short)l2;
  }
}

#define ARGMIN4(C, BASE, BEST, SECOND, BIDXV)               \
  {                                                         \
    _Pragma("unroll")                                       \
    for (int r = 0; r < 4; ++r) {                           \
      float v = (C)[r];                                     \
      bool lt = v < (BEST);                                 \
      float mn = fminf((SECOND), v);                        \
      (SECOND) = lt ? (BEST) : mn;                          \
      (BIDXV)  = lt ? ((BASE) + r) : (BIDXV);               \
      (BEST)   = lt ? v : (BEST);                           \
    }                                                       \
  }

// ---- kernel A: persistent-codebook MFMA + rescan + fused epilogue ----------
__global__ __launch_bounds__(1024) void vq_mfma(
    const float* __restrict__ z_e, const float* __restrict__ emb,
    const unsigned short* __restrict__ efrag, const float* __restrict__ esq_g,
    float* __restrict__ out_zq, float* __restrict__ out_idx,
    float* __restrict__ block_loss) {
  __shared__ float esql[K];                         // 2 KB
  __shared__ __align__(16) short lds_e[65536];      // 128 KB: all 32 tiles
  __shared__ int   sIdx[512];                       // 2 KB (per-wave slices)
  __shared__ float wsm[16];

  const int t  = threadIdx.x;                       // 0..1023
  const int l  = t & 63;
  const int wu = __builtin_amdgcn_readfirstlane(t >> 6);  // wave 0..15
  const int g  = l >> 4, g4 = g << 2;
  const int blk0 = blockIdx.x * 1024;               // this block's tokens

  if (t < K) esql[t] = esq_g[t];

  const bf16x8* EF = reinterpret_cast<const bf16x8*>(efrag);
  // Stage the whole codebook frag array: 8 rounds x 16KB (1024 thr x 16B).
#pragma unroll
  for (int r = 0; r < 8; ++r)
    GLDS16(EF + r * 1024 + t, &lds_e[r * 8192 + wu * 512]);
  asm volatile("s_waitcnt vmcnt(0)" ::: "memory");
  __builtin_amdgcn_s_barrier();                     // one-time; none after

  float blsum = 0.f;

  for (int pass = 0; pass < 2; ++pass) {
    const int tok0 = blk0 + pass * 512 + wu * 32;   // wave's 32 tokens

    // z frags for rows tok0+(l&15) [A] and +16 [B]. RNE split = efrag's.
    bf16x8 zh0A, zl0A, zh1A, zl1A, zh0B, zl0B, zh1B, zl1B;
    {
      const int rowA = tok0 + (l & 15);
      const float* zp = z_e + (size_t)rowA * D + g * 8;
      float4 q0 = *reinterpret_cast<const float4*>(zp);
      float4 q1 = *reinterpret_cast<const float4*>(zp + 4);
      float4 q2 = *reinterpret_cast<const float4*>(zp + 32);
      float4 q3 = *reinterpret_cast<const float4*>(zp + 36);
      split8(q0, q1, zh0A, zl0A);
      split8(q2, q3, zh1A, zl1A);
      zp += (size_t)16 * D;                         // rowB = rowA + 16
      q0 = *reinterpret_cast<const float4*>(zp);
      q1 = *reinterpret_cast<const float4*>(zp + 4);
      q2 = *reinterpret_cast<const float4*>(zp + 32);
      q3 = *reinterpret_cast<const float4*>(zp + 36);
      split8(q0, q1, zh0B, zl0B);
      split8(q2, q3, zh1B, zl1B);
    }

    float bestA = 3.402823466e38f, secondA = 3.402823466e38f;
    float bestB = 3.402823466e38f, secondB = 3.402823466e38f;
    int idxA = 0, idxB = 0;

#pragma unroll 2
    for (int tile = 0; tile < 32; ++tile) {         // ascending code order
      const bf16x8* tb =
          reinterpret_cast<const bf16x8*>(&lds_e[(size_t)tile * 2048]);
      f32x4 CA = *reinterpret_cast<const f32x4*>(&esql[tile * 16 + g4]);
      f32x4 CB = CA;
      bf16x8 e0h = tb[l], e0l = tb[64 + l];
      bf16x8 e1h = tb[128 + l], e1l = tb[192 + l];
      __builtin_amdgcn_s_setprio(1);
      CA = __builtin_amdgcn_mfma_f32_16x16x32_bf16(e0h, zh0A, CA, 0, 0, 0);
      CB = __builtin_amdgcn_mfma_f32_16x16x32_bf16(e0h, zh0B, CB, 0, 0, 0);
      CA = __builtin_amdgcn_mfma_f32_16x16x32_bf16(e0h, zl0A, CA, 0, 0, 0);
      CB = __builtin_amdgcn_mfma_f32_16x16x32_bf16(e0h, zl0B, CB, 0, 0, 0);
      CA = __builtin_amdgcn_mfma_f32_16x16x32_bf16(e0l, zh0A, CA, 0, 0, 0);
      CB = __builtin_amdgcn_mfma_f32_16x16x32_bf16(e0l, zh0B, CB, 0, 0, 0);
      CA = __builtin_amdgcn_mfma_f32_16x16x32_bf16(e1h, zh1A, CA, 0, 0, 0);
      CB = __builtin_amdgcn_mfma_f32_16x16x32_bf16(e1h, zh1B, CB, 0, 0, 0);
      CA = __builtin_amdgcn_mfma_f32_16x16x32_bf16(e1h, zl1A, CA, 0, 0, 0);
      CB = __builtin_amdgcn_mfma_f32_16x16x32_bf16(e1h, zl1B, CB, 0, 0, 0);
      CA = __builtin_amdgcn_mfma_f32_16x16x32_bf16(e1l, zh1A, CA, 0, 0, 0);
      CB = __builtin_amdgcn_mfma_f32_16x16x32_bf16(e1l, zh1B, CB, 0, 0, 0);
      __builtin_amdgcn_s_setprio(0);

      const int base = tile * 16 + g4;
      ARGMIN4(CA, base, bestA, secondA, idxA)
      ARGMIN4(CB, base, bestB, secondB, idxB)
    }

    // Reduce across lanes {l, l^16, l^32, l^48}; ties -> smaller code.
#pragma unroll
    for (int mask = 16; mask <= 32; mask <<= 1) {
      float ob, os; int oi; bool take; float hi2;
      ob = __shfl_xor(bestA, mask); oi = __shfl_xor(idxA, mask);
      os = __shfl_xor(secondA, mask);
      hi2 = fmaxf(bestA, ob);
      secondA = fminf(secondA, fminf(os, hi2));
      take = (ob < bestA) || (ob == bestA && oi < idxA);
      bestA = take ? ob : bestA; idxA = take ? oi : idxA;

      ob = __shfl_xor(bestB, mask); oi = __shfl_xor(idxB, mask);
      os = __shfl_xor(secondB, mask);
      hi2 = fmaxf(bestB, ob);
      secondB = fminf(secondB, fminf(os, hi2));
      take = (ob < bestB) || (ob == bestB && oi < idxB);
      bestB = take ? ob : bestB; idxB = take ? oi : idxB;
    }

    if (l < 16) {
      sIdx[wu * 32 + l]      = idxA;
      sIdx[wu * 32 + 16 + l] = idxB;
    }

    // Inline exact rescan of flagged tokens (same-wave ballot loop).
    {
      bool fA = (l < 16) && ((secondA - bestA) < THRESH);
      bool fB = (l < 16) && ((secondB - bestB) < THRESH);
      unsigned long long ba = __ballot(fA);
      unsigned long long bb = __ballot(fB);
      unsigned mask = (unsigned)((ba & 0xFFFFull) | ((bb & 0xFFFFull) << 16));
      while (mask) {
        const int j = __builtin_ctz(mask);
        mask &= mask - 1;
        const int n = tok0 + j;
        const float4* zr =
            reinterpret_cast<const float4*>(z_e + (size_t)n * D);
        float best = 3.402823466e38f; int bid = 0;
#pragma unroll 1
        for (int half2 = 0; half2 < 2; ++half2) {
          float acc[4];
#pragma unroll
          for (int m = 0; m < 4; ++m) acc[m] = 0.f;
#pragma unroll 1
          for (int i = 0; i < 16; ++i) {
            float4 z4 = zr[i];                     // uniform addr broadcast
#pragma unroll
            for (int m = 0; m < 4; ++m) {
              const float4 e4 = *reinterpret_cast<const float4*>(
                  emb + (size_t)(l + 64 * (half2 * 4 + m)) * D + 4 * i);
              acc[m] = fmaf(z4.x, e4.x, acc[m]);
              acc[m] = fmaf(z4.y, e4.y, acc[m]);
              acc[m] = fmaf(z4.z, e4.z, acc[m]);
              acc[m] = fmaf(z4.w, e4.w, acc[m]);
            }
          }
#pragma unroll
          for (int m = 0; m < 4; ++m) {
            const int code = l + 64 * (half2 * 4 + m);
            float s = fmaf(-2.f, acc[m], esq_g[code]);
            if (s < best) { best = s; bid = code; }
          }
        }
#pragma unroll
        for (int mk = 1; mk <= 32; mk <<= 1) {     // lexicographic min
          float ob = __shfl_xor(best, mk);
          int   oi = __shfl_xor(bid, mk);
          bool take = (ob < best) || (ob == best && oi < bid);
          best = take ? ob : best;
          bid  = take ? oi : bid;
        }
        if (l == 0) sIdx[wu * 32 + j] = bid;       // same-wave patch
      }
    }
    // No barrier: sIdx[wu*32..+32) produced and consumed by wave wu only.

    // Fused epilogue: 2 lanes/token within the wave.
    {
      const int tk = l >> 1, h = l & 1;
      const int n = tok0 + tk;
      const int bi = sIdx[wu * 32 + tk];
      const float4* er =
          reinterpret_cast<const float4*>(emb + (size_t)bi * D);
      const float4* zr =
          reinterpret_cast<const float4*>(z_e + (size_t)n * D);
      float4* orow = reinterpret_cast<float4*>(out_zq + (size_t)n * D);
      float lsum = 0.f;
#pragma unroll
      for (int j = 0; j < 8; ++j) {
        int i = h * 8 + j;
        float4 Q = er[i], Z = zr[i];
        float dx = Q.x - Z.x, dy = Q.y - Z.y, dz = Q.z - Z.z, dw = Q.w - Z.w;
        float4 st;
        st.x = Z.x + dx; st.y = Z.y + dy; st.z = Z.z + dz; st.w = Z.w + dw;
        orow[i] = st;
        lsum = fmaf(dx, dx, lsum); lsum = fmaf(dy, dy, lsum);
        lsum = fmaf(dz, dz, lsum); lsum = fmaf(dw, dw, lsum);
      }
      if (h == 0) out_idx[n] = (float)bi;
      float s = lsum;
#pragma unroll
      for (int off = 32; off > 0; off >>= 1) s += __shfl_xor(s, off, 64);
      blsum += s;                                  // uniform across lanes
    }
  }

  if (l == 0) wsm[wu] = blsum;
  __syncthreads();
  if (t == 0) {
    float s = 0.f;
#pragma unroll
    for (int i = 0; i < 16; ++i) s += wsm[i];      // fixed ascending order
    block_loss[blockIdx.x] = s;
  }
}

// ---- finalize loss (deterministic tree, 256 partials) ----------------------
__global__ __launch_bounds__(256) void loss_finalize(
    const float* __restrict__ bl, float* __restrict__ out_loss) {
  __shared__ float sm[256];
  const int t = threadIdx.x;
  sm[t] = bl[t];
  __syncthreads();
#pragma unroll
  for (int off = 128; off > 0; off >>= 1) {
    if (t < off) sm[t] += sm[t + off];
    __syncthreads();
  }
  if (t == 0) out_loss[0] = sm[0] * (1.0f / 16777216.0f);  // /(N*D)
}

extern "C" void kernel_launch(void* const* d_in, const int* in_sizes, int n_in,
                              void* d_out, int out_size, void* d_ws, size_t ws_size,
                              hipStream_t stream) {
  const float* z_e = (const float*)d_in[0];
  const float* emb = (const float*)d_in[1];

  float* out      = (float*)d_out;
  float* out_zq   = out;                          // N*D
  float* out_idx  = out + (size_t)N_TOK * D;      // N
  float* out_loss = out_idx + N_TOK;              // 1

  char* wsb = (char*)d_ws;
  float*          esqp = (float*)(wsb + WS_ESQ);
  float*          bl   = (float*)(wsb + WS_BL);
  unsigned short* ef   = (unsigned short*)(wsb + WS_EFRAG);

  prep_kernel<<<64, 512, 0, stream>>>(emb, ef, esqp);
  vq_mfma<<<NBLK_A, 1024, 0, stream>>>(z_e, emb, ef, esqp, out_zq, out_idx, bl);
  loss_finalize<<<1, 256, 0, stream>>>(bl, out_loss);
}